// Round 1
// baseline (8433.879 us; speedup 1.0000x reference)
//
#include <hip/hip_runtime.h>

#define N_NODES 20000
#define N_EDGES 320000
#define MSG_ROW 576
#define MSG_OFF 11520000   // N_NODES * 576 : sc region of d_out doubles as msg accumulator

__device__ __forceinline__ float silu_f(float x) {
    return x * (1.0f / (1.0f + __expf(-x)));
}

// one 64x64 MLP layer: dst[t][e] = silu(scale * sum_u src[u][e] * W[u*64+t])
__device__ __forceinline__ void mlp_layer(const float* src, float* dst,
                                          const float* __restrict__ W,
                                          float scale, int c0, int e0) {
    float a2[4][4];
#pragma unroll
    for (int i = 0; i < 4; ++i)
#pragma unroll
        for (int j = 0; j < 4; ++j) a2[i][j] = 0.f;

#pragma unroll 8
    for (int u = 0; u < 64; ++u) {
        const float4 h4 = *(const float4*)&src[(u << 6) + e0];
        const float4 w4 = *(const float4*)&W[(u << 6) + c0];
        const float hv[4] = {h4.x, h4.y, h4.z, h4.w};
        const float wv[4] = {w4.x, w4.y, w4.z, w4.w};
#pragma unroll
        for (int i = 0; i < 4; ++i)
#pragma unroll
            for (int j = 0; j < 4; ++j) a2[i][j] += wv[i] * hv[j];
    }
#pragma unroll
    for (int i = 0; i < 4; ++i) {
        float4 v;
        v.x = silu_f(a2[i][0] * scale);
        v.y = silu_f(a2[i][1] * scale);
        v.z = silu_f(a2[i][2] * scale);
        v.w = silu_f(a2[i][3] * scale);
        *(float4*)&dst[((c0 + i) << 6) + e0] = v;
    }
}

__global__ __launch_bounds__(256, 4)
void edge_kernel(const float* __restrict__ length,   // E x 8
                 const float* __restrict__ nf,       // N x 64
                 const float* __restrict__ ea,       // E x 9
                 const float* __restrict__ W1,       // 8 x 64
                 const float* __restrict__ W2,       // 64 x 64
                 const float* __restrict__ W3,       // 64 x 64
                 const float* __restrict__ W4,       // 64 x 192
                 const int*   __restrict__ eidx,     // 2 x E
                 float* __restrict__ msg)            // N x 576 accumulator
{
    __shared__ float bufA[4096];
    __shared__ float bufB[4096];
    __shared__ float lenS[512];   // [k][e]
    __shared__ float Ys[576];     // [e][m]
    __shared__ int   sendS[64];
    __shared__ int   recvS[64];

    const int tid = threadIdx.x;
    const int tx = tid & 15;        // channel quad id
    const int ty = tid >> 4;        // edge quad id
    const int c0 = tx << 2;
    const int e0 = ty << 2;
    const int ebase = blockIdx.x << 6;

    // stage length transposed -> [k][e]
    for (int i = tid; i < 512; i += 256) {
        const int e = i >> 3, k = i & 7;
        lenS[(k << 6) + e] = length[((ebase + e) << 3) + k];
    }
    // stage edge_attributes rows (linear layout == [e][m])
    for (int i = tid; i < 576; i += 256) Ys[i] = ea[ebase * 9 + i];
    if (tid < 64) {
        sendS[tid] = eidx[ebase + tid];
        recvS[tid] = eidx[N_EDGES + ebase + tid];
    }
    __syncthreads();

    // ---- layer 1: 8 -> 64 ----
    {
        float a2[4][4];
#pragma unroll
        for (int i = 0; i < 4; ++i)
#pragma unroll
            for (int j = 0; j < 4; ++j) a2[i][j] = 0.f;
#pragma unroll
        for (int k = 0; k < 8; ++k) {
            const float4 h4 = *(const float4*)&lenS[(k << 6) + e0];
            const float4 w4 = *(const float4*)&W1[(k << 6) + c0];
            const float hv[4] = {h4.x, h4.y, h4.z, h4.w};
            const float wv[4] = {w4.x, w4.y, w4.z, w4.w};
#pragma unroll
            for (int i = 0; i < 4; ++i)
#pragma unroll
                for (int j = 0; j < 4; ++j) a2[i][j] += wv[i] * hv[j];
        }
        const float s1 = 0.35355339059327373f;   // 1/sqrt(8)
#pragma unroll
        for (int i = 0; i < 4; ++i) {
            float4 v;
            v.x = silu_f(a2[i][0] * s1);
            v.y = silu_f(a2[i][1] * s1);
            v.z = silu_f(a2[i][2] * s1);
            v.w = silu_f(a2[i][3] * s1);
            *(float4*)&bufA[((c0 + i) << 6) + e0] = v;
        }
    }
    __syncthreads();

    // ---- layer 2, layer 3 ----
    mlp_layer(bufA, bufB, W2, 0.125f, c0, e0);
    __syncthreads();
    mlp_layer(bufB, bufA, W3, 0.125f, c0, e0);
    __syncthreads();

    // ---- layer 4: 64 -> 192 (no silu), fused outer product + scatter ----
    float wacc[3][4][4];
#pragma unroll
    for (int l = 0; l < 3; ++l)
#pragma unroll
        for (int i = 0; i < 4; ++i)
#pragma unroll
            for (int j = 0; j < 4; ++j) wacc[l][i][j] = 0.f;

#pragma unroll 4
    for (int u = 0; u < 64; ++u) {
        const float4 h4 = *(const float4*)&bufA[(u << 6) + e0];
        const float hv[4] = {h4.x, h4.y, h4.z, h4.w};
#pragma unroll
        for (int l = 0; l < 3; ++l) {
            const float4 w4 = *(const float4*)&W4[u * 192 + (l << 6) + c0];
            const float wv[4] = {w4.x, w4.y, w4.z, w4.w};
#pragma unroll
            for (int i = 0; i < 4; ++i)
#pragma unroll
                for (int j = 0; j < 4; ++j) wacc[l][i][j] += wv[i] * hv[j];
        }
    }

#pragma unroll
    for (int j = 0; j < 4; ++j) {
        const int e = e0 + j;
        const int snd = sendS[e];
        const int rcv = recvS[e];
        const float4 nf4 = *(const float4*)&nf[(snd << 6) + c0];
        const float nfv[4] = {nf4.x, nf4.y, nf4.z, nf4.w};
        float* mrow = msg + rcv * MSG_ROW;
        const float y0 = Ys[e * 9 + 0];
        float y1[3], y2[5];
#pragma unroll
        for (int m = 0; m < 3; ++m) y1[m] = Ys[e * 9 + 1 + m];
#pragma unroll
        for (int m = 0; m < 5; ++m) y2[m] = Ys[e * 9 + 4 + m];
#pragma unroll
        for (int i = 0; i < 4; ++i) {
            const int c = c0 + i;
            const float wx0 = wacc[0][i][j] * 0.125f * nfv[i];
            const float wx1 = wacc[1][i][j] * 0.125f * nfv[i];
            const float wx2 = wacc[2][i][j] * 0.125f * nfv[i];
            atomicAdd(&mrow[c], wx0 * y0);
#pragma unroll
            for (int m = 0; m < 3; ++m) atomicAdd(&mrow[64 + c * 3 + m], wx1 * y1[m]);
#pragma unroll
            for (int m = 0; m < 5; ++m) atomicAdd(&mrow[256 + c * 5 + m], wx2 * y2[m]);
        }
    }
}

__global__ __launch_bounds__(256, 4)
void node_kernel(const float* __restrict__ nf,    // N x 64
                 const float* __restrict__ na,    // N x 4
                 const float* __restrict__ Wl,    // 3 x 64 x 64
                 const float* __restrict__ Wsc,   // 4 x 64 x 64
                 float* __restrict__ out)         // [message | sc(=msg accum)]
{
    __shared__ float ms[4][576];
    __shared__ float fs[4][64];
    const int tid = threadIdx.x;
    const int wid = tid >> 6;
    const int v   = tid & 63;
    const int n   = (blockIdx.x << 2) + wid;
    const float* msg = out + MSG_OFF;

#pragma unroll
    for (int j = 0; j < 9; ++j)
        ms[wid][(j << 6) + v] = msg[n * MSG_ROW + (j << 6) + v];
    fs[wid][v] = nf[(n << 6) + v];
    __syncthreads();

    float o9[9];
#pragma unroll
    for (int j = 0; j < 9; ++j) o9[j] = 0.f;
    const float* m0 = &ms[wid][0];
    const float* m1 = &ms[wid][64];
    const float* m2 = &ms[wid][256];

#pragma unroll 8
    for (int u = 0; u < 64; ++u) {
        const float w0 = Wl[(u << 6) + v];
        const float w1 = Wl[4096 + (u << 6) + v];
        const float w2 = Wl[8192 + (u << 6) + v];
        o9[0] += m0[u] * w0;
        o9[1] += m1[u * 3 + 0] * w1;
        o9[2] += m1[u * 3 + 1] * w1;
        o9[3] += m1[u * 3 + 2] * w1;
        o9[4] += m2[u * 5 + 0] * w2;
        o9[5] += m2[u * 5 + 1] * w2;
        o9[6] += m2[u * 5 + 2] * w2;
        o9[7] += m2[u * 5 + 3] * w2;
        o9[8] += m2[u * 5 + 4] * w2;
    }
    // message output: out[n*576 + v*9 + j], scale 1/sqrt(64)=0.125
#pragma unroll
    for (int j = 0; j < 9; ++j) out[n * MSG_ROW + v * 9 + j] = o9[j] * 0.125f;

    // sc0[n][v] = (1/16) * sum_a attr[a] * sum_u feat[u] * Wsc[a][u][v]
    const float a0 = na[(n << 2) + 0];
    const float a1 = na[(n << 2) + 1];
    const float a2 = na[(n << 2) + 2];
    const float a3 = na[(n << 2) + 3];
    float sacc = 0.f;
#pragma unroll 8
    for (int u = 0; u < 64; ++u) {
        const float f = fs[wid][u];
        sacc += f * (a0 * Wsc[(u << 6) + v] + a1 * Wsc[4096 + (u << 6) + v] +
                     a2 * Wsc[8192 + (u << 6) + v] + a3 * Wsc[12288 + (u << 6) + v]);
    }
    float* scrow = out + MSG_OFF + n * MSG_ROW;
    scrow[v] = sacc * 0.0625f;
#pragma unroll
    for (int j = 1; j < 9; ++j) scrow[(j << 6) + v] = 0.f;
}

extern "C" void kernel_launch(void* const* d_in, const int* in_sizes, int n_in,
                              void* d_out, int out_size, void* d_ws, size_t ws_size,
                              hipStream_t stream) {
    const float* length = (const float*)d_in[0];
    const float* nfeat  = (const float*)d_in[1];
    const float* nattr  = (const float*)d_in[2];
    const float* eattr  = (const float*)d_in[3];
    const float* W1     = (const float*)d_in[4];
    const float* W2     = (const float*)d_in[5];
    const float* W3     = (const float*)d_in[6];
    const float* W4     = (const float*)d_in[7];
    const float* Wl     = (const float*)d_in[8];
    const float* Wsc    = (const float*)d_in[9];
    const int*   eidx   = (const int*)d_in[10];
    float* out = (float*)d_out;

    // zero the msg accumulator (sc half of d_out)
    hipMemsetAsync(out + MSG_OFF, 0, (size_t)N_NODES * MSG_ROW * sizeof(float), stream);

    edge_kernel<<<N_EDGES / 64, 256, 0, stream>>>(length, nfeat, eattr, W1, W2, W3, W4,
                                                  eidx, out + MSG_OFF);
    node_kernel<<<N_NODES / 4, 256, 0, stream>>>(nfeat, nattr, Wl, Wsc, out);
}

// Round 2
// 472.751 us; speedup vs baseline: 17.8400x; 17.8400x over previous
//
#include <hip/hip_runtime.h>

#define N_NODES 20000
#define N_EDGES 320000
#define MSG_ROW 576
#define MSG_OFF 11520000   // N_NODES * 576 : sc region of d_out doubles as msg buffer

__device__ __forceinline__ float silu_f(float x) {
    return x * (1.0f / (1.0f + __expf(-x)));
}

// one 64x64 MLP layer: dst[t][e] = silu(scale * sum_u src[u][e] * W[u*64+t])
__device__ __forceinline__ void mlp_layer(const float* src, float* dst,
                                          const float* __restrict__ W,
                                          float scale, int c0, int e0) {
    float a2[4][4];
#pragma unroll
    for (int i = 0; i < 4; ++i)
#pragma unroll
        for (int j = 0; j < 4; ++j) a2[i][j] = 0.f;

#pragma unroll 8
    for (int u = 0; u < 64; ++u) {
        const float4 h4 = *(const float4*)&src[(u << 6) + e0];
        const float4 w4 = *(const float4*)&W[(u << 6) + c0];
        const float hv[4] = {h4.x, h4.y, h4.z, h4.w};
        const float wv[4] = {w4.x, w4.y, w4.z, w4.w};
#pragma unroll
        for (int i = 0; i < 4; ++i)
#pragma unroll
            for (int j = 0; j < 4; ++j) a2[i][j] += wv[i] * hv[j];
    }
#pragma unroll
    for (int i = 0; i < 4; ++i) {
        float4 v;
        v.x = silu_f(a2[i][0] * scale);
        v.y = silu_f(a2[i][1] * scale);
        v.z = silu_f(a2[i][2] * scale);
        v.w = silu_f(a2[i][3] * scale);
        *(float4*)&dst[((c0 + i) << 6) + e0] = v;
    }
}

// ============================ CSR build ============================

__global__ __launch_bounds__(256)
void hist_kernel(const int* __restrict__ eidx, int* __restrict__ counts) {
    const int e = blockIdx.x * 256 + threadIdx.x;
    if (e < N_EDGES) atomicAdd(&counts[eidx[N_EDGES + e]], 1);
}

__global__ __launch_bounds__(1024)
void scan_kernel(const int* __restrict__ counts, int* __restrict__ offsets,
                 int* __restrict__ cursor) {
    __shared__ int sm[1024];
    __shared__ int carry;
    const int tid = threadIdx.x;
    if (tid == 0) carry = 0;
    __syncthreads();
    for (int base = 0; base < N_NODES; base += 1024) {
        const int idx = base + tid;
        const int v = (idx < N_NODES) ? counts[idx] : 0;
        sm[tid] = v;
        __syncthreads();
        for (int off = 1; off < 1024; off <<= 1) {
            const int t = (tid >= off) ? sm[tid - off] : 0;
            __syncthreads();
            sm[tid] += t;
            __syncthreads();
        }
        const int excl = sm[tid] - v + carry;
        if (idx < N_NODES) { offsets[idx] = excl; cursor[idx] = excl; }
        __syncthreads();
        if (tid == 1023) carry += sm[1023];
        __syncthreads();
    }
    if (tid == 0) offsets[N_NODES] = carry;
}

__global__ __launch_bounds__(256)
void scatter_kernel(const int* __restrict__ eidx, int* __restrict__ cursor,
                    int* __restrict__ order) {
    const int e = blockIdx.x * 256 + threadIdx.x;
    if (e < N_EDGES) {
        const int pos = atomicAdd(&cursor[eidx[N_EDGES + e]], 1);
        order[pos] = e;
    }
}

// ============================ edge MLP -> wx ============================

__global__ __launch_bounds__(256, 4)
void edge_mlp_kernel(const float* __restrict__ length,   // E x 8
                     const float* __restrict__ nf,       // N x 64
                     const float* __restrict__ W1,
                     const float* __restrict__ W2,
                     const float* __restrict__ W3,
                     const float* __restrict__ W4,
                     const int*   __restrict__ eidx,
                     float* __restrict__ wx)             // E x 192
{
    __shared__ float bufA[4096];
    __shared__ float bufB[4096];
    __shared__ float lenS[512];   // [k][e]
    __shared__ int   sendS[64];

    const int tid = threadIdx.x;
    const int tx = tid & 15;
    const int ty = tid >> 4;
    const int c0 = tx << 2;
    const int e0 = ty << 2;
    const int ebase = blockIdx.x << 6;

    for (int i = tid; i < 512; i += 256) {
        const int e = i >> 3, k = i & 7;
        lenS[(k << 6) + e] = length[((ebase + e) << 3) + k];
    }
    if (tid < 64) sendS[tid] = eidx[ebase + tid];
    __syncthreads();

    // layer 1: 8 -> 64
    {
        float a2[4][4];
#pragma unroll
        for (int i = 0; i < 4; ++i)
#pragma unroll
            for (int j = 0; j < 4; ++j) a2[i][j] = 0.f;
#pragma unroll
        for (int k = 0; k < 8; ++k) {
            const float4 h4 = *(const float4*)&lenS[(k << 6) + e0];
            const float4 w4 = *(const float4*)&W1[(k << 6) + c0];
            const float hv[4] = {h4.x, h4.y, h4.z, h4.w};
            const float wv[4] = {w4.x, w4.y, w4.z, w4.w};
#pragma unroll
            for (int i = 0; i < 4; ++i)
#pragma unroll
                for (int j = 0; j < 4; ++j) a2[i][j] += wv[i] * hv[j];
        }
        const float s1 = 0.35355339059327373f;   // 1/sqrt(8)
#pragma unroll
        for (int i = 0; i < 4; ++i) {
            float4 v;
            v.x = silu_f(a2[i][0] * s1);
            v.y = silu_f(a2[i][1] * s1);
            v.z = silu_f(a2[i][2] * s1);
            v.w = silu_f(a2[i][3] * s1);
            *(float4*)&bufA[((c0 + i) << 6) + e0] = v;
        }
    }
    __syncthreads();

    mlp_layer(bufA, bufB, W2, 0.125f, c0, e0);
    __syncthreads();
    mlp_layer(bufB, bufA, W3, 0.125f, c0, e0);
    __syncthreads();

    // layer 4: 64 -> 192 (no silu)
    float wacc[3][4][4];
#pragma unroll
    for (int l = 0; l < 3; ++l)
#pragma unroll
        for (int i = 0; i < 4; ++i)
#pragma unroll
            for (int j = 0; j < 4; ++j) wacc[l][i][j] = 0.f;

#pragma unroll 4
    for (int u = 0; u < 64; ++u) {
        const float4 h4 = *(const float4*)&bufA[(u << 6) + e0];
        const float hv[4] = {h4.x, h4.y, h4.z, h4.w};
#pragma unroll
        for (int l = 0; l < 3; ++l) {
            const float4 w4 = *(const float4*)&W4[u * 192 + (l << 6) + c0];
            const float wv[4] = {w4.x, w4.y, w4.z, w4.w};
#pragma unroll
            for (int i = 0; i < 4; ++i)
#pragma unroll
                for (int j = 0; j < 4; ++j) wacc[l][i][j] += wv[i] * hv[j];
        }
    }

    // wx[e][l*64+c] = 0.125 * w * nf[sender][c]  (coalesced float4 stores)
#pragma unroll
    for (int j = 0; j < 4; ++j) {
        const int e = e0 + j;
        const int snd = sendS[e];
        const float4 nf4 = *(const float4*)&nf[(snd << 6) + c0];
        const float nfv[4] = {nf4.x, nf4.y, nf4.z, nf4.w};
        float* wrow = wx + (size_t)(ebase + e) * 192;
#pragma unroll
        for (int l = 0; l < 3; ++l) {
            float4 v;
            v.x = wacc[l][0][j] * 0.125f * nfv[0];
            v.y = wacc[l][1][j] * 0.125f * nfv[1];
            v.z = wacc[l][2][j] * 0.125f * nfv[2];
            v.w = wacc[l][3][j] * 0.125f * nfv[3];
            *(float4*)&wrow[(l << 6) + c0] = v;
        }
    }
}

// ============================ gather per node ============================

__global__ __launch_bounds__(256, 8)
void gather_kernel(const float* __restrict__ wx,       // E x 192
                   const float* __restrict__ ea,       // E x 9
                   const int* __restrict__ offsets,    // N+1
                   const int* __restrict__ order,      // E
                   float* __restrict__ msg)            // N x 576
{
    const int tid = threadIdx.x;
    const int wid = tid >> 6;
    const int v   = tid & 63;
    const int n   = (blockIdx.x << 2) + wid;
    const int beg = offsets[n];
    const int end = offsets[n + 1];

    float a0 = 0.f, a1[3] = {0.f, 0.f, 0.f}, a2[5] = {0.f, 0.f, 0.f, 0.f, 0.f};
    for (int k = beg; k < end; ++k) {
        int e = order[k];
        e = __builtin_amdgcn_readfirstlane(e);   // wave-uniform -> scalar loads for y
        const float* wrow = wx + (size_t)e * 192;
        const float x0 = wrow[v];
        const float x1 = wrow[64 + v];
        const float x2 = wrow[128 + v];
        const float* y = ea + e * 9;
        a0 += x0 * y[0];
#pragma unroll
        for (int m = 0; m < 3; ++m) a1[m] += x1 * y[1 + m];
#pragma unroll
        for (int m = 0; m < 5; ++m) a2[m] += x2 * y[4 + m];
    }
    float* mrow = msg + (size_t)n * MSG_ROW;
    mrow[v] = a0;
#pragma unroll
    for (int m = 0; m < 3; ++m) mrow[64 + v * 3 + m] = a1[m];
#pragma unroll
    for (int m = 0; m < 5; ++m) mrow[256 + v * 5 + m] = a2[m];
}

// ============================ node transform ============================

__global__ __launch_bounds__(256, 4)
void node_kernel(const float* __restrict__ nf,    // N x 64
                 const float* __restrict__ na,    // N x 4
                 const float* __restrict__ Wl,    // 3 x 64 x 64
                 const float* __restrict__ Wsc,   // 4 x 64 x 64
                 float* __restrict__ out)         // [message | sc(=msg buffer)]
{
    __shared__ float ms[4][576];
    __shared__ float fs[4][64];
    const int tid = threadIdx.x;
    const int wid = tid >> 6;
    const int v   = tid & 63;
    const int n   = (blockIdx.x << 2) + wid;
    const float* msg = out + MSG_OFF;

#pragma unroll
    for (int j = 0; j < 9; ++j)
        ms[wid][(j << 6) + v] = msg[n * MSG_ROW + (j << 6) + v];
    fs[wid][v] = nf[(n << 6) + v];
    __syncthreads();

    float o9[9];
#pragma unroll
    for (int j = 0; j < 9; ++j) o9[j] = 0.f;
    const float* m0 = &ms[wid][0];
    const float* m1 = &ms[wid][64];
    const float* m2 = &ms[wid][256];

#pragma unroll 8
    for (int u = 0; u < 64; ++u) {
        const float w0 = Wl[(u << 6) + v];
        const float w1 = Wl[4096 + (u << 6) + v];
        const float w2 = Wl[8192 + (u << 6) + v];
        o9[0] += m0[u] * w0;
        o9[1] += m1[u * 3 + 0] * w1;
        o9[2] += m1[u * 3 + 1] * w1;
        o9[3] += m1[u * 3 + 2] * w1;
        o9[4] += m2[u * 5 + 0] * w2;
        o9[5] += m2[u * 5 + 1] * w2;
        o9[6] += m2[u * 5 + 2] * w2;
        o9[7] += m2[u * 5 + 3] * w2;
        o9[8] += m2[u * 5 + 4] * w2;
    }
#pragma unroll
    for (int j = 0; j < 9; ++j) out[n * MSG_ROW + v * 9 + j] = o9[j] * 0.125f;

    const float a0 = na[(n << 2) + 0];
    const float a1 = na[(n << 2) + 1];
    const float a2 = na[(n << 2) + 2];
    const float a3 = na[(n << 2) + 3];
    float sacc = 0.f;
#pragma unroll 8
    for (int u = 0; u < 64; ++u) {
        const float f = fs[wid][u];
        sacc += f * (a0 * Wsc[(u << 6) + v] + a1 * Wsc[4096 + (u << 6) + v] +
                     a2 * Wsc[8192 + (u << 6) + v] + a3 * Wsc[12288 + (u << 6) + v]);
    }
    float* scrow = out + MSG_OFF + n * MSG_ROW;
    scrow[v] = sacc * 0.0625f;
#pragma unroll
    for (int j = 1; j < 9; ++j) scrow[(j << 6) + v] = 0.f;
}

// ============================ fallback (atomic) path ============================

__global__ __launch_bounds__(256, 4)
void edge_kernel_atomic(const float* __restrict__ length,
                        const float* __restrict__ nf,
                        const float* __restrict__ ea,
                        const float* __restrict__ W1,
                        const float* __restrict__ W2,
                        const float* __restrict__ W3,
                        const float* __restrict__ W4,
                        const int*   __restrict__ eidx,
                        float* __restrict__ msg)
{
    __shared__ float bufA[4096];
    __shared__ float bufB[4096];
    __shared__ float lenS[512];
    __shared__ float Ys[576];
    __shared__ int   sendS[64];
    __shared__ int   recvS[64];

    const int tid = threadIdx.x;
    const int tx = tid & 15;
    const int ty = tid >> 4;
    const int c0 = tx << 2;
    const int e0 = ty << 2;
    const int ebase = blockIdx.x << 6;

    for (int i = tid; i < 512; i += 256) {
        const int e = i >> 3, k = i & 7;
        lenS[(k << 6) + e] = length[((ebase + e) << 3) + k];
    }
    for (int i = tid; i < 576; i += 256) Ys[i] = ea[ebase * 9 + i];
    if (tid < 64) {
        sendS[tid] = eidx[ebase + tid];
        recvS[tid] = eidx[N_EDGES + ebase + tid];
    }
    __syncthreads();

    {
        float a2[4][4];
#pragma unroll
        for (int i = 0; i < 4; ++i)
#pragma unroll
            for (int j = 0; j < 4; ++j) a2[i][j] = 0.f;
#pragma unroll
        for (int k = 0; k < 8; ++k) {
            const float4 h4 = *(const float4*)&lenS[(k << 6) + e0];
            const float4 w4 = *(const float4*)&W1[(k << 6) + c0];
            const float hv[4] = {h4.x, h4.y, h4.z, h4.w};
            const float wv[4] = {w4.x, w4.y, w4.z, w4.w};
#pragma unroll
            for (int i = 0; i < 4; ++i)
#pragma unroll
                for (int j = 0; j < 4; ++j) a2[i][j] += wv[i] * hv[j];
        }
        const float s1 = 0.35355339059327373f;
#pragma unroll
        for (int i = 0; i < 4; ++i) {
            float4 v;
            v.x = silu_f(a2[i][0] * s1);
            v.y = silu_f(a2[i][1] * s1);
            v.z = silu_f(a2[i][2] * s1);
            v.w = silu_f(a2[i][3] * s1);
            *(float4*)&bufA[((c0 + i) << 6) + e0] = v;
        }
    }
    __syncthreads();
    mlp_layer(bufA, bufB, W2, 0.125f, c0, e0);
    __syncthreads();
    mlp_layer(bufB, bufA, W3, 0.125f, c0, e0);
    __syncthreads();

    float wacc[3][4][4];
#pragma unroll
    for (int l = 0; l < 3; ++l)
#pragma unroll
        for (int i = 0; i < 4; ++i)
#pragma unroll
            for (int j = 0; j < 4; ++j) wacc[l][i][j] = 0.f;
#pragma unroll 4
    for (int u = 0; u < 64; ++u) {
        const float4 h4 = *(const float4*)&bufA[(u << 6) + e0];
        const float hv[4] = {h4.x, h4.y, h4.z, h4.w};
#pragma unroll
        for (int l = 0; l < 3; ++l) {
            const float4 w4 = *(const float4*)&W4[u * 192 + (l << 6) + c0];
            const float wv[4] = {w4.x, w4.y, w4.z, w4.w};
#pragma unroll
            for (int i = 0; i < 4; ++i)
#pragma unroll
                for (int j = 0; j < 4; ++j) wacc[l][i][j] += wv[i] * hv[j];
        }
    }

#pragma unroll
    for (int j = 0; j < 4; ++j) {
        const int e = e0 + j;
        const int snd = sendS[e];
        const int rcv = recvS[e];
        const float4 nf4 = *(const float4*)&nf[(snd << 6) + c0];
        const float nfv[4] = {nf4.x, nf4.y, nf4.z, nf4.w};
        float* mrow = msg + rcv * MSG_ROW;
        const float y0 = Ys[e * 9 + 0];
        float y1[3], y2[5];
#pragma unroll
        for (int m = 0; m < 3; ++m) y1[m] = Ys[e * 9 + 1 + m];
#pragma unroll
        for (int m = 0; m < 5; ++m) y2[m] = Ys[e * 9 + 4 + m];
#pragma unroll
        for (int i = 0; i < 4; ++i) {
            const int c = c0 + i;
            const float wx0 = wacc[0][i][j] * 0.125f * nfv[i];
            const float wx1 = wacc[1][i][j] * 0.125f * nfv[i];
            const float wx2 = wacc[2][i][j] * 0.125f * nfv[i];
            atomicAdd(&mrow[c], wx0 * y0);
#pragma unroll
            for (int m = 0; m < 3; ++m) atomicAdd(&mrow[64 + c * 3 + m], wx1 * y1[m]);
#pragma unroll
            for (int m = 0; m < 5; ++m) atomicAdd(&mrow[256 + c * 5 + m], wx2 * y2[m]);
        }
    }
}

extern "C" void kernel_launch(void* const* d_in, const int* in_sizes, int n_in,
                              void* d_out, int out_size, void* d_ws, size_t ws_size,
                              hipStream_t stream) {
    const float* length = (const float*)d_in[0];
    const float* nfeat  = (const float*)d_in[1];
    const float* nattr  = (const float*)d_in[2];
    const float* eattr  = (const float*)d_in[3];
    const float* W1     = (const float*)d_in[4];
    const float* W2     = (const float*)d_in[5];
    const float* W3     = (const float*)d_in[6];
    const float* W4     = (const float*)d_in[7];
    const float* Wl     = (const float*)d_in[8];
    const float* Wsc    = (const float*)d_in[9];
    const int*   eidx   = (const int*)d_in[10];
    float* out = (float*)d_out;

    // ws layout: wx[E*192] | counts[N] | offsets[N+1] | cursor[N] | order[E]
    float* wx      = (float*)d_ws;
    int*   counts  = (int*)(wx + (size_t)N_EDGES * 192);
    int*   offsets = counts + N_NODES;
    int*   cursor  = offsets + N_NODES + 1;
    int*   order   = cursor + N_NODES;
    const size_t need = (size_t)N_EDGES * 192 * 4 +
                        (size_t)(N_NODES * 3 + 1 + N_EDGES) * 4;

    if (ws_size >= need) {
        hipMemsetAsync(counts, 0, N_NODES * sizeof(int), stream);
        hist_kernel<<<N_EDGES / 256, 256, 0, stream>>>(eidx, counts);
        scan_kernel<<<1, 1024, 0, stream>>>(counts, offsets, cursor);
        scatter_kernel<<<N_EDGES / 256, 256, 0, stream>>>(eidx, cursor, order);
        edge_mlp_kernel<<<N_EDGES / 64, 256, 0, stream>>>(length, nfeat, W1, W2, W3, W4,
                                                          eidx, wx);
        gather_kernel<<<N_NODES / 4, 256, 0, stream>>>(wx, eattr, offsets, order,
                                                       out + MSG_OFF);
        node_kernel<<<N_NODES / 4, 256, 0, stream>>>(nfeat, nattr, Wl, Wsc, out);
    } else {
        // fallback: atomic scatter path
        hipMemsetAsync(out + MSG_OFF, 0, (size_t)N_NODES * MSG_ROW * sizeof(float), stream);
        edge_kernel_atomic<<<N_EDGES / 64, 256, 0, stream>>>(length, nfeat, eattr,
                                                             W1, W2, W3, W4, eidx,
                                                             out + MSG_OFF);
        node_kernel<<<N_NODES / 4, 256, 0, stream>>>(nfeat, nattr, Wl, Wsc, out);
    }
}